// Round 1
// baseline (251.183 us; speedup 1.0000x reference)
//
#include <hip/hip_runtime.h>

typedef unsigned short u16;
typedef unsigned int u32;

using bf16x8 = __bf16 __attribute__((ext_vector_type(8)));
using f32x4  = float  __attribute__((ext_vector_type(4)));

#define LDS_SPACE __attribute__((address_space(3)))
#define GLB_SPACE __attribute__((address_space(1)))

static __device__ __forceinline__ u16 f2bf(float f) {
  union { float f; u32 u; } c; c.f = f;
  u32 u = c.u;
  u32 r = (u + 0x7fffu + ((u >> 16) & 1u)) >> 16;   // RNE
  return (u16)r;
}
static __device__ __forceinline__ float bf2f(u16 u) {
  union { u32 u; float f; } c; c.u = ((u32)u) << 16;
  return c.f;
}

// ---------------- f32 -> bf16 convert (x) ----------------
__global__ __launch_bounds__(256) void cvt_f32_bf16_k(const float* __restrict__ src,
                                                      u16* __restrict__ dst, int n4) {
  int i = blockIdx.x * 256 + threadIdx.x;
  if (i >= n4) return;
  float4 v = ((const float4*)src)[i];
  ushort4 o;
  o.x = f2bf(v.x); o.y = f2bf(v.y); o.z = f2bf(v.z); o.w = f2bf(v.w);
  ((ushort4*)dst)[i] = o;
}

// ---------------- transpose + convert (weights) ----------------
// src: f32 [R][C]  ->  dst: bf16 [C][R]
__global__ __launch_bounds__(256) void transpose_cvt_k(const float* __restrict__ src,
                                                       u16* __restrict__ dst, int R, int C) {
  __shared__ float t[32][33];
  int lx = threadIdx.x & 31, ly = threadIdx.x >> 5;
  int r0 = blockIdx.y * 32, c0 = blockIdx.x * 32;
  #pragma unroll
  for (int i = 0; i < 32; i += 8)
    t[ly + i][lx] = src[(size_t)(r0 + ly + i) * C + c0 + lx];
  __syncthreads();
  #pragma unroll
  for (int i = 0; i < 32; i += 8)
    dst[(size_t)(c0 + ly + i) * R + r0 + lx] = f2bf(t[lx][ly + i]);
}

// ---------------- GEMM: C[M][N] = A[M][K] * Bt[N][K]^T  (bf16 in, fp32 acc) ----
template <typename OutT>
__global__ __launch_bounds__(256) void gemm_bt_k(const u16* __restrict__ A,
                                                 const u16* __restrict__ Bt,
                                                 OutT* __restrict__ C,
                                                 int M, int N, int K) {
  __shared__ u16 As[128 * 32];
  __shared__ u16 Bs[128 * 32];
  const int tid = threadIdx.x, lane = tid & 63, wave = tid >> 6;
  const int wr = wave >> 1, wc = wave & 1;
  const int bm = blockIdx.y, bn = blockIdx.x;
  const int l15 = lane & 15, lq = lane >> 4;
  f32x4 acc[4][4] = {};

  // staging: each wave stages 2KB of A and 2KB of B per K-step (2 insts each)
  const int srow = wave * 32 + (lane >> 2);          // + i*16
  const int scol = (lane & 3) * 8;
  const u16* Ag = A + (size_t)(bm * 128 + srow) * K + scol;
  const u16* Bg = Bt + (size_t)(bn * 128 + srow) * K + scol;
  u16* AsW = As + wave * 1024;                       // + i*512 elements
  u16* BsW = Bs + wave * 1024;

  for (int k0 = 0; k0 < K; k0 += 32) {
    __syncthreads();
    #pragma unroll
    for (int i = 0; i < 2; ++i) {
      __builtin_amdgcn_global_load_lds((const GLB_SPACE u32*)(Ag + k0 + (size_t)i * 16 * K),
                                       (LDS_SPACE u32*)(AsW + i * 512), 16, 0, 0);
      __builtin_amdgcn_global_load_lds((const GLB_SPACE u32*)(Bg + k0 + (size_t)i * 16 * K),
                                       (LDS_SPACE u32*)(BsW + i * 512), 16, 0, 0);
    }
    __syncthreads();
    bf16x8 a[4], b[4];
    const u16* ap = As + (wr * 64 + l15) * 32 + lq * 8;
    const u16* bp = Bs + (wc * 64 + l15) * 32 + lq * 8;
    #pragma unroll
    for (int m = 0; m < 4; ++m) a[m] = *(const bf16x8*)(ap + m * 16 * 32);
    #pragma unroll
    for (int n = 0; n < 4; ++n) b[n] = *(const bf16x8*)(bp + n * 16 * 32);
    #pragma unroll
    for (int m = 0; m < 4; ++m)
      #pragma unroll
      for (int n = 0; n < 4; ++n)
        acc[m][n] = __builtin_amdgcn_mfma_f32_16x16x32_bf16(a[m], b[n], acc[m][n], 0, 0, 0);
  }

  const int r0 = bm * 128 + wr * 64 + lq * 4;
  const int c0 = bn * 128 + wc * 64 + l15;
  #pragma unroll
  for (int m = 0; m < 4; ++m)
    #pragma unroll
    for (int n = 0; n < 4; ++n)
      #pragma unroll
      for (int r = 0; r < 4; ++r) {
        float v = acc[m][n][r];
        size_t off = (size_t)(r0 + m * 16 + r) * N + (c0 + n * 16);
        if constexpr (sizeof(OutT) == 2) ((u16*)C)[off] = f2bf(v);
        else C[off] = v;
      }
}

// ---------------- RoPE on Q (cols 0..2047) and K (cols 2048..2559) of Y ------
__global__ __launch_bounds__(256) void rope_k(u16* __restrict__ Y,
                                              const float* __restrict__ freq) {
  int idx = blockIdx.x * 256 + threadIdx.x;   // pair id: 2048 * 40 * 32 total
  int s = idx / 1280;                         // 40 heads * 32 pairs
  int rem = idx - s * 1280;
  int h = rem >> 5;
  int i = rem & 31;
  int col = (h < 32) ? (h * 64 + 2 * i) : (2048 + (h - 32) * 64 + 2 * i);
  float ang = freq[s * 32 + i];
  float sn, cs;
  sincosf(ang, &sn, &cs);
  size_t base = (size_t)s * 3072 + col;
  float e = bf2f(Y[base]), o = bf2f(Y[base + 1]);
  Y[base]     = f2bf(e * cs - o * sn);
  Y[base + 1] = f2bf(e * sn + o * cs);
}

// ---------------- Flash attention: causal GQA ----------------
// Y: [2048][3072] bf16 (Q | K | V), Out: [2048][2048] bf16
__global__ __launch_bounds__(256) void attn_k(const u16* __restrict__ Y,
                                              u16* __restrict__ Out) {
  constexpr int YLD = 3072, PAD = 80;
  __shared__ u16 Qs[64 * PAD];
  __shared__ u16 Ks[64 * PAD];
  __shared__ u16 Vt[64 * PAD];
  __shared__ u16 Ps[64 * PAD];
  const int qh = blockIdx.x, qt = blockIdx.y;
  const int kvh = qh >> 2;
  const int q0 = qt * 64;
  const int tid = threadIdx.x, lane = tid & 63, wave = tid >> 6;
  const int l15 = lane & 15, lq = lane >> 4;

  // stage Q once
  #pragma unroll
  for (int rnd = 0; rnd < 2; ++rnd) {
    int e = rnd * 2048 + tid * 8;
    int row = e >> 6, col = e & 63;
    *(uint4*)&Qs[row * PAD + col] =
        *(const uint4*)&Y[(size_t)(q0 + row) * YLD + qh * 64 + col];
  }

  float m_r[4] = { -INFINITY, -INFINITY, -INFINITY, -INFINITY };
  float l_r[4] = { 0.f, 0.f, 0.f, 0.f };
  f32x4 acc_o[4] = {};

  const int ntiles = qt + 1;
  for (int t = 0; t < ntiles; ++t) {
    const int t0 = t * 64;
    __syncthreads();
    // stage K (row-major) and V (transposed)
    #pragma unroll
    for (int rnd = 0; rnd < 2; ++rnd) {
      int e = rnd * 2048 + tid * 8;
      int row = e >> 6, col = e & 63;
      *(uint4*)&Ks[row * PAD + col] =
          *(const uint4*)&Y[(size_t)(t0 + row) * YLD + 2048 + kvh * 64 + col];
      uint4 v = *(const uint4*)&Y[(size_t)(t0 + row) * YLD + 2560 + kvh * 64 + col];
      const u16* vs = (const u16*)&v;
      #pragma unroll
      for (int j = 0; j < 8; ++j) Vt[(col + j) * PAD + row] = vs[j];
    }
    __syncthreads();

    // S = Q K^T for this wave's 16 q-rows
    f32x4 sc[4] = {};
    const u16* qp = Qs + (wave * 16 + l15) * PAD + lq * 8;
    #pragma unroll
    for (int kk = 0; kk < 2; ++kk) {
      bf16x8 a = *(const bf16x8*)(qp + kk * 32);
      #pragma unroll
      for (int n = 0; n < 4; ++n) {
        bf16x8 b = *(const bf16x8*)(Ks + (n * 16 + l15) * PAD + kk * 32 + lq * 8);
        sc[n] = __builtin_amdgcn_mfma_f32_16x16x32_bf16(a, b, sc[n], 0, 0, 0);
      }
    }

    // mask + scale + online softmax (rows owned per (lq, r))
    const int kvc = t0 + l15;                    // + n*16
    const int qrow = q0 + wave * 16 + lq * 4;    // + r
    #pragma unroll
    for (int r = 0; r < 4; ++r) {
      float mx = -INFINITY;
      #pragma unroll
      for (int n = 0; n < 4; ++n) {
        float sv = sc[n][r] * 0.125f;
        if (kvc + n * 16 > qrow + r) sv = -INFINITY;
        sc[n][r] = sv;
        mx = fmaxf(mx, sv);
      }
      #pragma unroll
      for (int off = 1; off < 16; off <<= 1) mx = fmaxf(mx, __shfl_xor(mx, off));
      float mnew = fmaxf(m_r[r], mx);
      float alpha = __expf(m_r[r] - mnew);       // exp(-inf - finite) = 0, no NaN
      float sum = 0.f;
      #pragma unroll
      for (int n = 0; n < 4; ++n) {
        float p = __expf(sc[n][r] - mnew);
        sc[n][r] = p;
        sum += p;
      }
      #pragma unroll
      for (int off = 1; off < 16; off <<= 1) sum += __shfl_xor(sum, off);
      l_r[r] = l_r[r] * alpha + sum;
      m_r[r] = mnew;
      #pragma unroll
      for (int n = 0; n < 4; ++n) acc_o[n][r] *= alpha;
    }

    // P -> LDS (bf16), then O += P V
    #pragma unroll
    for (int n = 0; n < 4; ++n)
      #pragma unroll
      for (int r = 0; r < 4; ++r)
        Ps[(wave * 16 + lq * 4 + r) * PAD + n * 16 + l15] = f2bf(sc[n][r]);

    const u16* pp = Ps + (wave * 16 + l15) * PAD + lq * 8;
    #pragma unroll
    for (int kk = 0; kk < 2; ++kk) {
      bf16x8 a = *(const bf16x8*)(pp + kk * 32);
      #pragma unroll
      for (int n = 0; n < 4; ++n) {
        bf16x8 b = *(const bf16x8*)(Vt + (n * 16 + l15) * PAD + kk * 32 + lq * 8);
        acc_o[n] = __builtin_amdgcn_mfma_f32_16x16x32_bf16(a, b, acc_o[n], 0, 0, 0);
      }
    }
  }

  const int orow = q0 + wave * 16 + lq * 4;
  const int ocol = qh * 64 + l15;
  #pragma unroll
  for (int n = 0; n < 4; ++n)
    #pragma unroll
    for (int r = 0; r < 4; ++r)
      Out[(size_t)(orow + r) * 2048 + ocol + n * 16] = f2bf(acc_o[n][r] / l_r[r]);
}

extern "C" void kernel_launch(void* const* d_in, const int* in_sizes, int n_in,
                              void* d_out, int out_size, void* d_ws, size_t ws_size,
                              hipStream_t stream) {
  const float* x    = (const float*)d_in[0];
  const float* freq = (const float*)d_in[1];
  // d_in[2] = mask (known causal tril; not read)
  const float* wq   = (const float*)d_in[3];
  const float* wk   = (const float*)d_in[4];
  const float* wv   = (const float*)d_in[5];
  const float* wo   = (const float*)d_in[6];
  float* out = (float*)d_out;

  u16* x_bf   = (u16*)d_ws;                       // 2048*2048
  u16* wqkv_t = x_bf + (size_t)2048 * 2048;       // [3072][2048] = wq^T | wk^T | wv^T
  u16* wo_t   = wqkv_t + (size_t)3072 * 2048;     // [2048][2048]
  u16* y      = wo_t + (size_t)2048 * 2048;       // [2048][3072] = Q | K | V
  u16* attn   = y + (size_t)2048 * 3072;          // [2048][2048]

  cvt_f32_bf16_k<<<4096, 256, 0, stream>>>(x, x_bf, 2048 * 2048 / 4);
  transpose_cvt_k<<<dim3(64, 64), 256, 0, stream>>>(wq, wqkv_t, 2048, 2048);
  transpose_cvt_k<<<dim3(16, 64), 256, 0, stream>>>(wk, wqkv_t + (size_t)2048 * 2048, 2048, 512);
  transpose_cvt_k<<<dim3(16, 64), 256, 0, stream>>>(wv, wqkv_t + (size_t)2560 * 2048, 2048, 512);
  transpose_cvt_k<<<dim3(64, 64), 256, 0, stream>>>(wo, wo_t, 2048, 2048);

  gemm_bt_k<u16><<<dim3(24, 16), 256, 0, stream>>>(x_bf, wqkv_t, y, 2048, 3072, 2048);
  rope_k<<<10240, 256, 0, stream>>>(y, freq);
  attn_k<<<dim3(32, 32), 256, 0, stream>>>(y, attn);
  gemm_bt_k<float><<<dim3(16, 16), 256, 0, stream>>>(attn, wo_t, out, 2048, 2048, 2048);
}

// Round 2
// 207.773 us; speedup vs baseline: 1.2089x; 1.2089x over previous
//
#include <hip/hip_runtime.h>

typedef unsigned short u16;
typedef unsigned int u32;

using bf16x8 = __bf16 __attribute__((ext_vector_type(8)));
using f32x4  = float  __attribute__((ext_vector_type(4)));

#define LDS_SPACE __attribute__((address_space(3)))
#define GLB_SPACE __attribute__((address_space(1)))

static __device__ __forceinline__ u16 f2bf(float f) {
  union { float f; u32 u; } c; c.f = f;
  u32 u = c.u;
  return (u16)((u + 0x7fffu + ((u >> 16) & 1u)) >> 16);   // RNE
}
static __device__ __forceinline__ float bf2f(u16 u) {
  union { u32 u; float f; } c; c.u = ((u32)u) << 16;
  return c.f;
}

static __device__ __forceinline__ void fence_barrier() {
  asm volatile("" ::: "memory");
  __builtin_amdgcn_s_barrier();
  asm volatile("" ::: "memory");
}

// ---------------- f32 -> bf16 convert (x) ----------------
__global__ __launch_bounds__(256) void cvt_f32_bf16_k(const float* __restrict__ src,
                                                      u16* __restrict__ dst, int n4) {
  int i = blockIdx.x * 256 + threadIdx.x;
  if (i >= n4) return;
  float4 v = ((const float4*)src)[i];
  ushort4 o;
  o.x = f2bf(v.x); o.y = f2bf(v.y); o.z = f2bf(v.z); o.w = f2bf(v.w);
  ((ushort4*)dst)[i] = o;
}

// ---------------- transpose + convert (weights) ----------------
// src: f32 [R][C]  ->  dst: bf16 [C][R]
__global__ __launch_bounds__(256) void transpose_cvt_k(const float* __restrict__ src,
                                                       u16* __restrict__ dst, int R, int C) {
  __shared__ float t[32][33];
  int lx = threadIdx.x & 31, ly = threadIdx.x >> 5;
  int r0 = blockIdx.y * 32, c0 = blockIdx.x * 32;
  #pragma unroll
  for (int i = 0; i < 32; i += 8)
    t[ly + i][lx] = src[(size_t)(r0 + ly + i) * C + c0 + lx];
  __syncthreads();
  #pragma unroll
  for (int i = 0; i < 32; i += 8)
    dst[(size_t)(c0 + ly + i) * R + r0 + lx] = f2bf(t[lx][ly + i]);
}

// ---------------- bf16 transpose of V region of Y -> Vt [512][2048] ---------
// Vt[c][s] = Y[s][2560 + c]
__global__ __launch_bounds__(256) void vtrans_k(const u16* __restrict__ Y,
                                                u16* __restrict__ Vt) {
  __shared__ u16 t[64][72];
  const int s0 = blockIdx.x * 64;      // 32
  const int c0 = blockIdx.y * 64;      // 8
  const int lx = threadIdx.x & 63, ly = threadIdx.x >> 6;  // ly 0..3
  #pragma unroll
  for (int i = 0; i < 64; i += 4)
    t[i + ly][lx] = Y[(size_t)(s0 + i + ly) * 3072 + 2560 + c0 + lx];
  __syncthreads();
  #pragma unroll
  for (int i = 0; i < 64; i += 4)
    Vt[(size_t)(c0 + i + ly) * 2048 + s0 + lx] = t[lx][i + ly];
}

// ---------------- GEMM: C[M][N] = A[M][K] * Bt[N][K]^T  (2-phase dbuf) -------
template <typename OutT>
__global__ __launch_bounds__(256) void gemm_bt_k(const u16* __restrict__ A,
                                                 const u16* __restrict__ Bt,
                                                 OutT* __restrict__ C,
                                                 int M, int N, int K) {
  __shared__ u16 As[2][128 * 32];
  __shared__ u16 Bs[2][128 * 32];
  const int tid = threadIdx.x, lane = tid & 63, wave = tid >> 6;
  const int wr = wave >> 1, wc = wave & 1;
  const int bm = blockIdx.y, bn = blockIdx.x;
  const int l15 = lane & 15, lq = lane >> 4;
  f32x4 acc[4][4] = {};

  const int srow = wave * 32 + (lane >> 2);
  const int scol = (lane & 3) * 8;
  const u16* Ag = A + (size_t)(bm * 128 + srow) * K + scol;
  const u16* Bg = Bt + (size_t)(bn * 128 + srow) * K + scol;

  auto stage = [&](int buf, int k0) {
    #pragma unroll
    for (int i = 0; i < 2; ++i) {
      __builtin_amdgcn_global_load_lds((const GLB_SPACE u32*)(Ag + k0 + (size_t)i * 16 * K),
                                       (LDS_SPACE u32*)&As[buf][wave * 1024 + i * 512], 16, 0, 0);
      __builtin_amdgcn_global_load_lds((const GLB_SPACE u32*)(Bg + k0 + (size_t)i * 16 * K),
                                       (LDS_SPACE u32*)&Bs[buf][wave * 1024 + i * 512], 16, 0, 0);
    }
  };

  stage(0, 0);
  for (int k0 = 0; k0 < K; k0 += 32) {
    const int cur = (k0 >> 5) & 1;
    fence_barrier();                               // release buf cur^1
    if (k0 + 32 < K) {
      stage(cur ^ 1, k0 + 32);
      asm volatile("s_waitcnt vmcnt(4)" ::: "memory");
    } else {
      asm volatile("s_waitcnt vmcnt(0)" ::: "memory");
    }
    fence_barrier();                               // acquire buf cur

    bf16x8 a[4], b[4];
    const u16* ap = &As[cur][(wr * 64 + l15) * 32 + lq * 8];
    const u16* bp = &Bs[cur][(wc * 64 + l15) * 32 + lq * 8];
    #pragma unroll
    for (int m = 0; m < 4; ++m) a[m] = *(const bf16x8*)(ap + m * 16 * 32);
    #pragma unroll
    for (int n = 0; n < 4; ++n) b[n] = *(const bf16x8*)(bp + n * 16 * 32);
    #pragma unroll
    for (int m = 0; m < 4; ++m)
      #pragma unroll
      for (int n = 0; n < 4; ++n)
        acc[m][n] = __builtin_amdgcn_mfma_f32_16x16x32_bf16(a[m], b[n], acc[m][n], 0, 0, 0);
  }

  const int r0 = bm * 128 + wr * 64 + lq * 4;
  const int c0 = bn * 128 + wc * 64 + l15;
  #pragma unroll
  for (int m = 0; m < 4; ++m)
    #pragma unroll
    for (int n = 0; n < 4; ++n)
      #pragma unroll
      for (int r = 0; r < 4; ++r) {
        float v = acc[m][n][r];
        size_t off = (size_t)(r0 + m * 16 + r) * N + (c0 + n * 16);
        if constexpr (sizeof(OutT) == 2) ((u16*)C)[off] = f2bf(v);
        else C[off] = v;
      }
}

// ---------------- RoPE on Q (cols 0..2047) and K (cols 2048..2559) of Y ------
__global__ __launch_bounds__(256) void rope_k(u16* __restrict__ Y,
                                              const float* __restrict__ freq) {
  int idx = blockIdx.x * 256 + threadIdx.x;   // pair id: 2048 * 40 * 32 total
  int s = idx / 1280;
  int rem = idx - s * 1280;
  int h = rem >> 5;
  int i = rem & 31;
  int col = (h < 32) ? (h * 64 + 2 * i) : (2048 + (h - 32) * 64 + 2 * i);
  float ang = freq[s * 32 + i];
  float sn, cs;
  sincosf(ang, &sn, &cs);
  size_t base = (size_t)s * 3072 + col;
  float e = bf2f(Y[base]), o = bf2f(Y[base + 1]);
  Y[base]     = f2bf(e * cs - o * sn);
  Y[base + 1] = f2bf(e * sn + o * cs);
}

// ---------------- Flash attention: causal GQA (swapped QK^T, dbuf K/V) -------
// Y: [2048][3072] bf16 (Q|K|V, roped), Vtg: [512][2048] bf16 (V^T), Out bf16.
__global__ __launch_bounds__(256) void attn_k(const u16* __restrict__ Y,
                                              const u16* __restrict__ Vtg,
                                              u16* __restrict__ Out) {
  __shared__ u16 Ks[2][64 * 64];
  __shared__ u16 Vts[2][64 * 64];
  __shared__ u32 Ps[4][16 * 36];

  const int qh = blockIdx.x;
  const int qt = 15 - (int)blockIdx.y;        // biggest tiles dispatched first
  const int kvh = qh >> 2;
  const int q0 = qt * 128;
  const int ntiles = 2 * qt + 2;

  const int tid = threadIdx.x;
  const int lane = tid & 63, w = tid >> 6;
  const int l15 = lane & 15, lq = lane >> 4;

  const int sub = lane >> 3;                  // row-within-1KB-inst
  const int csw = ((lane & 7) ^ sub) << 3;    // pre-swizzled source col (u16)

  auto stageKV = [&](int buf, int t) {
    const int t0 = t * 64;
    #pragma unroll
    for (int i = 0; i < 2; ++i) {
      const int r = w * 16 + i * 8;
      const u16* gk = Y + (size_t)(t0 + r + sub) * 3072 + 2048 + kvh * 64 + csw;
      __builtin_amdgcn_global_load_lds((const GLB_SPACE u32*)gk,
                                       (LDS_SPACE u32*)&Ks[buf][r * 64], 16, 0, 0);
      const u16* gv = Vtg + (size_t)(kvh * 64 + r + sub) * 2048 + t0 + csw;
      __builtin_amdgcn_global_load_lds((const GLB_SPACE u32*)gv,
                                       (LDS_SPACE u32*)&Vts[buf][r * 64], 16, 0, 0);
    }
  };

  stageKV(0, 0);

  // Q fragments straight from global (roped): B-frag rows q=l15, cols d
  bf16x8 qf[2][2];
  #pragma unroll
  for (int qs = 0; qs < 2; ++qs)
    #pragma unroll
    for (int kk = 0; kk < 2; ++kk)
      qf[qs][kk] = *(const bf16x8*)&Y[(size_t)(q0 + w * 32 + qs * 16 + l15) * 3072 +
                                      qh * 64 + kk * 32 + lq * 8];

  float m_[2] = { -INFINITY, -INFINITY };
  float l_[2] = { 0.f, 0.f };
  f32x4 accO[2][4] = {};

  constexpr float SC = 0.18033688011112042f;  // log2(e) / sqrt(64)

  for (int t = 0; t < ntiles; ++t) {
    const int cur = t & 1;
    fence_barrier();                          // release buf cur^1
    if (t + 1 < ntiles) {
      stageKV(cur ^ 1, t + 1);
      asm volatile("s_waitcnt vmcnt(4)" ::: "memory");
    } else {
      asm volatile("s_waitcnt vmcnt(0)" ::: "memory");
    }
    fence_barrier();                          // acquire buf cur

    const int t0 = t * 64;
    if (t0 > q0 + w * 32 + 31) continue;      // wave fully masked for this tile

    const u16* Kb = Ks[cur];
    const u16* Vb = Vts[cur];

    // S^T = K Q^T : col = q (l15), row = kv (4*lq + r)
    f32x4 sc[2][4] = {};
    #pragma unroll
    for (int kk = 0; kk < 2; ++kk) {
      #pragma unroll
      for (int kt = 0; kt < 4; ++kt) {
        const int rr = kt * 16 + l15;
        bf16x8 a = *(const bf16x8*)&Kb[rr * 64 + ((kk * 32 + lq * 8) ^ ((rr & 7) << 3))];
        sc[0][kt] = __builtin_amdgcn_mfma_f32_16x16x32_bf16(a, qf[0][kk], sc[0][kt], 0, 0, 0);
        sc[1][kt] = __builtin_amdgcn_mfma_f32_16x16x32_bf16(a, qf[1][kk], sc[1][kt], 0, 0, 0);
      }
    }

    // V^T A-fragments (shared by both q-subtiles)
    bf16x8 vf[4][2];
    #pragma unroll
    for (int dt = 0; dt < 4; ++dt)
      #pragma unroll
      for (int c = 0; c < 2; ++c) {
        const int rr = dt * 16 + l15;
        vf[dt][c] = *(const bf16x8*)&Vb[rr * 64 + ((c * 32 + lq * 8) ^ ((rr & 7) << 3))];
      }

    #pragma unroll
    for (int qs = 0; qs < 2; ++qs) {
      const int qsmin = q0 + w * 32 + qs * 16;
      if (t0 > qsmin + 15) continue;          // subtile fully masked
      const int qrow = qsmin + l15;
      const bool domask = (t0 + 63) > qsmin;

      float mx = -INFINITY;
      #pragma unroll
      for (int n = 0; n < 4; ++n)
        #pragma unroll
        for (int r = 0; r < 4; ++r) {
          float v = sc[qs][n][r] * SC;
          if (domask && (t0 + n * 16 + lq * 4 + r) > qrow) v = -INFINITY;
          sc[qs][n][r] = v;
          mx = fmaxf(mx, v);
        }
      mx = fmaxf(mx, __shfl_xor(mx, 16));
      mx = fmaxf(mx, __shfl_xor(mx, 32));
      const float mnew = fmaxf(m_[qs], mx);
      const float alpha = exp2f(m_[qs] - mnew);
      float sum = 0.f;
      u32* pp = &Ps[w][l15 * 36 + lq * 2];
      #pragma unroll
      for (int n = 0; n < 4; ++n)
        #pragma unroll
        for (int h = 0; h < 2; ++h) {
          float p0 = exp2f(sc[qs][n][2 * h] - mnew);
          float p1 = exp2f(sc[qs][n][2 * h + 1] - mnew);
          sum += p0 + p1;
          pp[n * 8 + h] = (u32)f2bf(p0) | ((u32)f2bf(p1) << 16);
        }
      sum += __shfl_xor(sum, 16);
      sum += __shfl_xor(sum, 32);
      l_[qs] = l_[qs] * alpha + sum;
      m_[qs] = mnew;
      #pragma unroll
      for (int dt = 0; dt < 4; ++dt) accO[qs][dt] *= alpha;

      // O^T += V^T P^T : B-frag = P rows (q=l15), cols kv
      const u16* p16 = (const u16*)Ps[w];
      #pragma unroll
      for (int c = 0; c < 2; ++c) {
        bf16x8 b = *(const bf16x8*)&p16[l15 * 72 + c * 32 + lq * 8];
        #pragma unroll
        for (int dt = 0; dt < 4; ++dt)
          accO[qs][dt] = __builtin_amdgcn_mfma_f32_16x16x32_bf16(vf[dt][c], b, accO[qs][dt], 0, 0, 0);
      }
    }
  }

  #pragma unroll
  for (int qs = 0; qs < 2; ++qs) {
    const int qrow = q0 + w * 32 + qs * 16 + l15;
    const float rl = 1.0f / l_[qs];
    #pragma unroll
    for (int dt = 0; dt < 4; ++dt) {
      ushort4 o;
      o.x = f2bf(accO[qs][dt][0] * rl);
      o.y = f2bf(accO[qs][dt][1] * rl);
      o.z = f2bf(accO[qs][dt][2] * rl);
      o.w = f2bf(accO[qs][dt][3] * rl);
      *(ushort4*)&Out[(size_t)qrow * 2048 + qh * 64 + dt * 16 + lq * 4] = o;
    }
  }
}

extern "C" void kernel_launch(void* const* d_in, const int* in_sizes, int n_in,
                              void* d_out, int out_size, void* d_ws, size_t ws_size,
                              hipStream_t stream) {
  const float* x    = (const float*)d_in[0];
  const float* freq = (const float*)d_in[1];
  // d_in[2] = mask (known causal tril; not read)
  const float* wq   = (const float*)d_in[3];
  const float* wk   = (const float*)d_in[4];
  const float* wv   = (const float*)d_in[5];
  const float* wo   = (const float*)d_in[6];
  float* out = (float*)d_out;

  u16* x_bf   = (u16*)d_ws;                       // 2048*2048  (reused as Vt later)
  u16* wqkv_t = x_bf + (size_t)2048 * 2048;       // [3072][2048]
  u16* wo_t   = wqkv_t + (size_t)3072 * 2048;     // [2048][2048]
  u16* y      = wo_t + (size_t)2048 * 2048;       // [2048][3072] = Q | K | V
  u16* attn   = y + (size_t)2048 * 3072;          // [2048][2048]
  u16* vt     = x_bf;                             // [512][2048]  (x_bf dead after QKV GEMM)

  cvt_f32_bf16_k<<<4096, 256, 0, stream>>>(x, x_bf, 2048 * 2048 / 4);
  transpose_cvt_k<<<dim3(64, 64), 256, 0, stream>>>(wq, wqkv_t, 2048, 2048);
  transpose_cvt_k<<<dim3(16, 64), 256, 0, stream>>>(wk, wqkv_t + (size_t)2048 * 2048, 2048, 512);
  transpose_cvt_k<<<dim3(16, 64), 256, 0, stream>>>(wv, wqkv_t + (size_t)2560 * 2048, 2048, 512);
  transpose_cvt_k<<<dim3(64, 64), 256, 0, stream>>>(wo, wo_t, 2048, 2048);

  gemm_bt_k<u16><<<dim3(24, 16), 256, 0, stream>>>(x_bf, wqkv_t, y, 2048, 3072, 2048);
  rope_k<<<10240, 256, 0, stream>>>(y, freq);
  vtrans_k<<<dim3(32, 8), 256, 0, stream>>>(y, vt);
  attn_k<<<dim3(32, 16), 256, 0, stream>>>(y, vt, attn);
  gemm_bt_k<float><<<dim3(16, 16), 256, 0, stream>>>(attn, wo_t, out, 2048, 2048, 2048);
}

// Round 3
// 202.598 us; speedup vs baseline: 1.2398x; 1.0255x over previous
//
#include <hip/hip_runtime.h>

typedef unsigned short u16;
typedef unsigned int u32;

using bf16x8 = __bf16 __attribute__((ext_vector_type(8)));
using f32x4  = float  __attribute__((ext_vector_type(4)));

#define LDS_SPACE __attribute__((address_space(3)))
#define GLB_SPACE __attribute__((address_space(1)))

static __device__ __forceinline__ u16 f2bf(float f) {
  union { float f; u32 u; } c; c.f = f;
  u32 u = c.u;
  return (u16)((u + 0x7fffu + ((u >> 16) & 1u)) >> 16);   // RNE
}
static __device__ __forceinline__ float bf2f(u16 u) {
  union { u32 u; float f; } c; c.u = ((u32)u) << 16;
  return c.f;
}

static __device__ __forceinline__ void fence_barrier() {
  asm volatile("" ::: "memory");
  __builtin_amdgcn_s_barrier();
  asm volatile("" ::: "memory");
}

// ---------------- f32 -> bf16 convert (x) ----------------
__global__ __launch_bounds__(256) void cvt_f32_bf16_k(const float* __restrict__ src,
                                                      u16* __restrict__ dst, int n4) {
  int i = blockIdx.x * 256 + threadIdx.x;
  if (i >= n4) return;
  float4 v = ((const float4*)src)[i];
  ushort4 o;
  o.x = f2bf(v.x); o.y = f2bf(v.y); o.z = f2bf(v.z); o.w = f2bf(v.w);
  ((ushort4*)dst)[i] = o;
}

// ---------------- transpose + convert (weights) ----------------
// src: f32 [R][C]  ->  dst: bf16 [C][R]
__global__ __launch_bounds__(256) void transpose_cvt_k(const float* __restrict__ src,
                                                       u16* __restrict__ dst, int R, int C) {
  __shared__ float t[32][33];
  int lx = threadIdx.x & 31, ly = threadIdx.x >> 5;
  int r0 = blockIdx.y * 32, c0 = blockIdx.x * 32;
  #pragma unroll
  for (int i = 0; i < 32; i += 8)
    t[ly + i][lx] = src[(size_t)(r0 + ly + i) * C + c0 + lx];
  __syncthreads();
  #pragma unroll
  for (int i = 0; i < 32; i += 8)
    dst[(size_t)(c0 + ly + i) * R + r0 + lx] = f2bf(t[lx][ly + i]);
}

// ---------------- bf16 transpose of V region of Y -> Vt [512][2048] ---------
__global__ __launch_bounds__(256) void vtrans_k(const u16* __restrict__ Y,
                                                u16* __restrict__ Vt) {
  __shared__ u16 t[64][72];
  const int s0 = blockIdx.x * 64;
  const int c0 = blockIdx.y * 64;
  const int lx = threadIdx.x & 63, ly = threadIdx.x >> 6;
  #pragma unroll
  for (int i = 0; i < 64; i += 4)
    t[i + ly][lx] = Y[(size_t)(s0 + i + ly) * 3072 + 2560 + c0 + lx];
  __syncthreads();
  #pragma unroll
  for (int i = 0; i < 64; i += 4)
    Vt[(size_t)(c0 + i + ly) * 2048 + s0 + lx] = t[lx][i + ly];
}

// ---------------- GEMM: C[M][N] = A[M][K] * Bt[N][K]^T  (2-phase dbuf) -------
template <typename OutT>
__global__ __launch_bounds__(256) void gemm_bt_k(const u16* __restrict__ A,
                                                 const u16* __restrict__ Bt,
                                                 OutT* __restrict__ C,
                                                 int M, int N, int K) {
  __shared__ u16 As[2][128 * 32];
  __shared__ u16 Bs[2][128 * 32];
  const int tid = threadIdx.x, lane = tid & 63, wave = tid >> 6;
  const int wr = wave >> 1, wc = wave & 1;
  const int bm = blockIdx.y, bn = blockIdx.x;
  const int l15 = lane & 15, lq = lane >> 4;
  f32x4 acc[4][4] = {};

  const int srow = wave * 32 + (lane >> 2);
  const int scol = (lane & 3) * 8;
  const u16* Ag = A + (size_t)(bm * 128 + srow) * K + scol;
  const u16* Bg = Bt + (size_t)(bn * 128 + srow) * K + scol;

  auto stage = [&](int buf, int k0) {
    #pragma unroll
    for (int i = 0; i < 2; ++i) {
      __builtin_amdgcn_global_load_lds((const GLB_SPACE u32*)(Ag + k0 + (size_t)i * 16 * K),
                                       (LDS_SPACE u32*)&As[buf][wave * 1024 + i * 512], 16, 0, 0);
      __builtin_amdgcn_global_load_lds((const GLB_SPACE u32*)(Bg + k0 + (size_t)i * 16 * K),
                                       (LDS_SPACE u32*)&Bs[buf][wave * 1024 + i * 512], 16, 0, 0);
    }
  };

  stage(0, 0);
  for (int k0 = 0; k0 < K; k0 += 32) {
    const int cur = (k0 >> 5) & 1;
    fence_barrier();
    if (k0 + 32 < K) {
      stage(cur ^ 1, k0 + 32);
      asm volatile("s_waitcnt vmcnt(4)" ::: "memory");
    } else {
      asm volatile("s_waitcnt vmcnt(0)" ::: "memory");
    }
    fence_barrier();

    bf16x8 a[4], b[4];
    const u16* ap = &As[cur][(wr * 64 + l15) * 32 + lq * 8];
    const u16* bp = &Bs[cur][(wc * 64 + l15) * 32 + lq * 8];
    #pragma unroll
    for (int m = 0; m < 4; ++m) a[m] = *(const bf16x8*)(ap + m * 16 * 32);
    #pragma unroll
    for (int n = 0; n < 4; ++n) b[n] = *(const bf16x8*)(bp + n * 16 * 32);
    #pragma unroll
    for (int m = 0; m < 4; ++m)
      #pragma unroll
      for (int n = 0; n < 4; ++n)
        acc[m][n] = __builtin_amdgcn_mfma_f32_16x16x32_bf16(a[m], b[n], acc[m][n], 0, 0, 0);
  }

  const int r0 = bm * 128 + wr * 64 + lq * 4;
  const int c0 = bn * 128 + wc * 64 + l15;
  #pragma unroll
  for (int m = 0; m < 4; ++m)
    #pragma unroll
    for (int n = 0; n < 4; ++n)
      #pragma unroll
      for (int r = 0; r < 4; ++r) {
        float v = acc[m][n][r];
        size_t off = (size_t)(r0 + m * 16 + r) * N + (c0 + n * 16);
        if constexpr (sizeof(OutT) == 2) ((u16*)C)[off] = f2bf(v);
        else C[off] = v;
      }
}

// ---------------- RoPE on Q (cols 0..2047) and K (cols 2048..2559) of Y ------
__global__ __launch_bounds__(256) void rope_k(u16* __restrict__ Y,
                                              const float* __restrict__ freq) {
  int idx = blockIdx.x * 256 + threadIdx.x;
  int s = idx / 1280;
  int rem = idx - s * 1280;
  int h = rem >> 5;
  int i = rem & 31;
  int col = (h < 32) ? (h * 64 + 2 * i) : (2048 + (h - 32) * 64 + 2 * i);
  float ang = freq[s * 32 + i];
  float sn, cs;
  sincosf(ang, &sn, &cs);
  size_t base = (size_t)s * 3072 + col;
  float e = bf2f(Y[base]), o = bf2f(Y[base + 1]);
  Y[base]     = f2bf(e * cs - o * sn);
  Y[base + 1] = f2bf(e * sn + o * cs);
}

// ---------------- Flash attention: causal GQA, barrier-free, K/V from L2 -----
// Y: [2048][3072] bf16 (Q|K|V roped), Vtg: [512][2048] bf16 (V^T), Out bf16.
// One wave per block; each wave owns 32 q-rows of one head.
__global__ __launch_bounds__(64, 3) void attn_k(const u16* __restrict__ Y,
                                                const u16* __restrict__ Vtg,
                                                u16* __restrict__ Out) {
  __shared__ u32 Ps[16 * 36];
  const int bx = blockIdx.x;
  const int qh = bx & 31;
  const int ws = 63 - (bx >> 5);              // big tiles dispatched first
  const int kvh = qh >> 2;
  const int q0w = ws * 32;
  const int ntiles = (q0w >> 6) + 1;
  const int lane = threadIdx.x & 63;
  const int l15 = lane & 15, lq = lane >> 4;

  bf16x8 qf[2][2];
  #pragma unroll
  for (int qs = 0; qs < 2; ++qs)
    #pragma unroll
    for (int kk = 0; kk < 2; ++kk)
      qf[qs][kk] = *(const bf16x8*)&Y[(size_t)(q0w + qs * 16 + l15) * 3072 +
                                      qh * 64 + kk * 32 + lq * 8];

  float m_[2] = { -INFINITY, -INFINITY };
  float l_[2] = { 0.f, 0.f };
  f32x4 accO[2][4] = {};
  constexpr float SC = 0.18033688011112042f;  // log2(e)/8

  const u16* Kg = Y + 2048 + kvh * 64 + (size_t)l15 * 3072 + lq * 8;
  const u16* Vg = Vtg + (size_t)(kvh * 64 + l15) * 2048 + lq * 8;

  for (int t = 0; t < ntiles; ++t) {
    const int t0 = t * 64;

    // K fragments direct from L2
    bf16x8 kf[2][4];
    #pragma unroll
    for (int kt = 0; kt < 4; ++kt)
      #pragma unroll
      for (int kk = 0; kk < 2; ++kk)
        kf[kk][kt] = *(const bf16x8*)&Kg[(size_t)(t0 + kt * 16) * 3072 + kk * 32];

    // S^T = K Q^T : col = q (l15), row = kv (lq*4 + r + kt*16)
    f32x4 sc[2][4] = {};
    #pragma unroll
    for (int kk = 0; kk < 2; ++kk)
      #pragma unroll
      for (int kt = 0; kt < 4; ++kt) {
        sc[0][kt] = __builtin_amdgcn_mfma_f32_16x16x32_bf16(kf[kk][kt], qf[0][kk], sc[0][kt], 0, 0, 0);
        sc[1][kt] = __builtin_amdgcn_mfma_f32_16x16x32_bf16(kf[kk][kt], qf[1][kk], sc[1][kt], 0, 0, 0);
      }

    // V^T fragments direct from L2 (latency hides under softmax)
    bf16x8 vf[4][2];
    #pragma unroll
    for (int dt = 0; dt < 4; ++dt)
      #pragma unroll
      for (int c = 0; c < 2; ++c)
        vf[dt][c] = *(const bf16x8*)&Vg[(size_t)(dt * 16) * 2048 + t0 + c * 32];

    const bool lastt = (t == ntiles - 1);

    #pragma unroll
    for (int qs = 0; qs < 2; ++qs) {
      const int qrow = q0w + qs * 16 + l15;
      if (lastt) {
        #pragma unroll
        for (int n = 0; n < 4; ++n)
          #pragma unroll
          for (int r = 0; r < 4; ++r)
            if (t0 + n * 16 + lq * 4 + r > qrow) sc[qs][n][r] = -INFINITY;
      }
      float mx = -INFINITY;
      #pragma unroll
      for (int n = 0; n < 4; ++n)
        #pragma unroll
        for (int r = 0; r < 4; ++r) mx = fmaxf(mx, sc[qs][n][r]);
      mx = fmaxf(mx, __shfl_xor(mx, 16));
      mx = fmaxf(mx, __shfl_xor(mx, 32));

      // defer-max: only rescale when the running max actually grows (>THR)
      if (__any(mx > m_[qs] + 40.0f)) {
        const float mnew = fmaxf(m_[qs], mx);
        const float alpha = exp2f((m_[qs] - mnew) * SC);
        l_[qs] *= alpha;
        #pragma unroll
        for (int dt = 0; dt < 4; ++dt) accO[qs][dt] *= alpha;
        m_[qs] = mnew;
      }
      const float mS = m_[qs] * SC;
      float sum = 0.f;
      u32* pp = &Ps[l15 * 36 + lq * 2];
      #pragma unroll
      for (int n = 0; n < 4; ++n)
        #pragma unroll
        for (int h = 0; h < 2; ++h) {
          float p0 = exp2f(sc[qs][n][2 * h]     * SC - mS);
          float p1 = exp2f(sc[qs][n][2 * h + 1] * SC - mS);
          sum += p0 + p1;
          u32 w;
          asm("v_cvt_pk_bf16_f32 %0, %1, %2" : "=v"(w) : "v"(p0), "v"(p1));
          pp[n * 8 + h] = w;
        }
      sum += __shfl_xor(sum, 16);
      sum += __shfl_xor(sum, 32);
      l_[qs] += sum;

      // O^T += V^T P^T : B-frag = P rows (q=l15), cols kv
      const u16* p16 = (const u16*)Ps;
      #pragma unroll
      for (int c = 0; c < 2; ++c) {
        bf16x8 b = *(const bf16x8*)&p16[l15 * 72 + c * 32 + lq * 8];
        #pragma unroll
        for (int dt = 0; dt < 4; ++dt)
          accO[qs][dt] = __builtin_amdgcn_mfma_f32_16x16x32_bf16(vf[dt][c], b, accO[qs][dt], 0, 0, 0);
      }
    }
  }

  #pragma unroll
  for (int qs = 0; qs < 2; ++qs) {
    const int qrow = q0w + qs * 16 + l15;
    const float rl = 1.0f / l_[qs];
    #pragma unroll
    for (int dt = 0; dt < 4; ++dt) {
      ushort4 o;
      o.x = f2bf(accO[qs][dt][0] * rl);
      o.y = f2bf(accO[qs][dt][1] * rl);
      o.z = f2bf(accO[qs][dt][2] * rl);
      o.w = f2bf(accO[qs][dt][3] * rl);
      *(ushort4*)&Out[(size_t)qrow * 2048 + qh * 64 + dt * 16 + lq * 4] = o;
    }
  }
}

extern "C" void kernel_launch(void* const* d_in, const int* in_sizes, int n_in,
                              void* d_out, int out_size, void* d_ws, size_t ws_size,
                              hipStream_t stream) {
  const float* x    = (const float*)d_in[0];
  const float* freq = (const float*)d_in[1];
  // d_in[2] = mask (known causal tril; not read)
  const float* wq   = (const float*)d_in[3];
  const float* wk   = (const float*)d_in[4];
  const float* wv   = (const float*)d_in[5];
  const float* wo   = (const float*)d_in[6];
  float* out = (float*)d_out;

  u16* x_bf   = (u16*)d_ws;                       // 2048*2048  (reused as Vt later)
  u16* wqkv_t = x_bf + (size_t)2048 * 2048;       // [3072][2048]
  u16* wo_t   = wqkv_t + (size_t)3072 * 2048;     // [2048][2048]
  u16* y      = wo_t + (size_t)2048 * 2048;       // [2048][3072] = Q | K | V
  u16* attn   = y + (size_t)2048 * 3072;          // [2048][2048]
  u16* vt     = x_bf;                             // [512][2048]  (x_bf dead after QKV GEMM)

  cvt_f32_bf16_k<<<4096, 256, 0, stream>>>(x, x_bf, 2048 * 2048 / 4);
  transpose_cvt_k<<<dim3(64, 64), 256, 0, stream>>>(wq, wqkv_t, 2048, 2048);
  transpose_cvt_k<<<dim3(16, 64), 256, 0, stream>>>(wk, wqkv_t + (size_t)2048 * 2048, 2048, 512);
  transpose_cvt_k<<<dim3(16, 64), 256, 0, stream>>>(wv, wqkv_t + (size_t)2560 * 2048, 2048, 512);
  transpose_cvt_k<<<dim3(64, 64), 256, 0, stream>>>(wo, wo_t, 2048, 2048);

  gemm_bt_k<u16><<<dim3(24, 16), 256, 0, stream>>>(x_bf, wqkv_t, y, 2048, 3072, 2048);
  rope_k<<<10240, 256, 0, stream>>>(y, freq);
  vtrans_k<<<dim3(32, 8), 256, 0, stream>>>(y, vt);
  attn_k<<<2048, 64, 0, stream>>>(y, vt, attn);
  gemm_bt_k<float><<<dim3(16, 16), 256, 0, stream>>>(attn, wo_t, out, 2048, 2048, 2048);
}

// Round 4
// 187.934 us; speedup vs baseline: 1.3365x; 1.0780x over previous
//
#include <hip/hip_runtime.h>

typedef unsigned short u16;
typedef unsigned int u32;

using bf16x8 = __bf16 __attribute__((ext_vector_type(8)));
using f32x4  = float  __attribute__((ext_vector_type(4)));

#define LDS_SPACE __attribute__((address_space(3)))
#define GLB_SPACE __attribute__((address_space(1)))

static __device__ __forceinline__ u16 f2bf(float f) {
  union { float f; u32 u; } c; c.f = f;
  u32 u = c.u;
  return (u16)((u + 0x7fffu + ((u >> 16) & 1u)) >> 16);   // RNE
}
static __device__ __forceinline__ float bf2f(u16 u) {
  union { u32 u; float f; } c; c.u = ((u32)u) << 16;
  return c.f;
}

static __device__ __forceinline__ void fence_barrier() {
  asm volatile("" ::: "memory");
  __builtin_amdgcn_s_barrier();
  asm volatile("" ::: "memory");
}

// ---------------- f32 -> bf16 convert (x) ----------------
__global__ __launch_bounds__(256) void cvt_f32_bf16_k(const float* __restrict__ src,
                                                      u16* __restrict__ dst, int n4) {
  int i = blockIdx.x * 256 + threadIdx.x;
  if (i >= n4) return;
  float4 v = ((const float4*)src)[i];
  ushort4 o;
  o.x = f2bf(v.x); o.y = f2bf(v.y); o.z = f2bf(v.z); o.w = f2bf(v.w);
  ((ushort4*)dst)[i] = o;
}

// ---------------- transpose + convert (weights) ----------------
__global__ __launch_bounds__(256) void transpose_cvt_k(const float* __restrict__ src,
                                                       u16* __restrict__ dst, int R, int C) {
  __shared__ float t[32][33];
  int lx = threadIdx.x & 31, ly = threadIdx.x >> 5;
  int r0 = blockIdx.y * 32, c0 = blockIdx.x * 32;
  #pragma unroll
  for (int i = 0; i < 32; i += 8)
    t[ly + i][lx] = src[(size_t)(r0 + ly + i) * C + c0 + lx];
  __syncthreads();
  #pragma unroll
  for (int i = 0; i < 32; i += 8)
    dst[(size_t)(c0 + ly + i) * R + r0 + lx] = f2bf(t[lx][ly + i]);
}

// ---------------- bf16 transpose of V region of Y -> Vt [512][2048] ---------
__global__ __launch_bounds__(256) void vtrans_k(const u16* __restrict__ Y,
                                                u16* __restrict__ Vt) {
  __shared__ u16 t[64][72];
  const int s0 = blockIdx.x * 64;
  const int c0 = blockIdx.y * 64;
  const int lx = threadIdx.x & 63, ly = threadIdx.x >> 6;
  #pragma unroll
  for (int i = 0; i < 64; i += 4)
    t[i + ly][lx] = Y[(size_t)(s0 + i + ly) * 3072 + 2560 + c0 + lx];
  __syncthreads();
  #pragma unroll
  for (int i = 0; i < 64; i += 4)
    Vt[(size_t)(c0 + i + ly) * 2048 + s0 + lx] = t[lx][i + ly];
}

// ------- GEMM: C[M][N] = A[M][K]*Bt[N][K]^T, BM=64 BN=128 (2-phase dbuf) ----
template <typename OutT>
__global__ __launch_bounds__(256) void gemm64_k(const u16* __restrict__ A,
                                                const u16* __restrict__ Bt,
                                                OutT* __restrict__ C,
                                                int M, int N, int K) {
  __shared__ u16 As[2][64 * 32];
  __shared__ u16 Bs[2][128 * 32];
  const int tid = threadIdx.x, lane = tid & 63, wave = tid >> 6;
  const int wr = wave >> 1, wc = wave & 1;
  const int bm = blockIdx.y, bn = blockIdx.x;
  const int l15 = lane & 15, lq = lane >> 4;
  f32x4 acc[2][4] = {};

  const int srow = lane >> 2;
  const int scol = (lane & 3) * 8;
  const u16* Ag = A + (size_t)(bm * 64 + wave * 16 + srow) * K + scol;
  const u16* Bg = Bt + (size_t)(bn * 128 + wave * 32 + srow) * K + scol;

  auto stage = [&](int buf, int k0) {
    __builtin_amdgcn_global_load_lds((const GLB_SPACE u32*)(Ag + k0),
                                     (LDS_SPACE u32*)&As[buf][wave * 512], 16, 0, 0);
    #pragma unroll
    for (int i = 0; i < 2; ++i)
      __builtin_amdgcn_global_load_lds((const GLB_SPACE u32*)(Bg + k0 + (size_t)i * 16 * K),
                                       (LDS_SPACE u32*)&Bs[buf][wave * 1024 + i * 512], 16, 0, 0);
  };

  stage(0, 0);
  for (int k0 = 0; k0 < K; k0 += 32) {
    const int cur = (k0 >> 5) & 1;
    fence_barrier();
    if (k0 + 32 < K) {
      stage(cur ^ 1, k0 + 32);
      asm volatile("s_waitcnt vmcnt(3)" ::: "memory");
    } else {
      asm volatile("s_waitcnt vmcnt(0)" ::: "memory");
    }
    fence_barrier();

    bf16x8 a[2], b[4];
    const u16* ap = &As[cur][(wr * 32 + l15) * 32 + lq * 8];
    const u16* bp = &Bs[cur][(wc * 64 + l15) * 32 + lq * 8];
    #pragma unroll
    for (int m = 0; m < 2; ++m) a[m] = *(const bf16x8*)(ap + m * 16 * 32);
    #pragma unroll
    for (int n = 0; n < 4; ++n) b[n] = *(const bf16x8*)(bp + n * 16 * 32);
    #pragma unroll
    for (int m = 0; m < 2; ++m)
      #pragma unroll
      for (int n = 0; n < 4; ++n)
        acc[m][n] = __builtin_amdgcn_mfma_f32_16x16x32_bf16(a[m], b[n], acc[m][n], 0, 0, 0);
  }

  const int r0 = bm * 64 + wr * 32 + lq * 4;
  const int c0 = bn * 128 + wc * 64 + l15;
  #pragma unroll
  for (int m = 0; m < 2; ++m)
    #pragma unroll
    for (int n = 0; n < 4; ++n)
      #pragma unroll
      for (int r = 0; r < 4; ++r) {
        float v = acc[m][n][r];
        size_t off = (size_t)(r0 + m * 16 + r) * N + (c0 + n * 16);
        if constexpr (sizeof(OutT) == 2) ((u16*)C)[off] = f2bf(v);
        else C[off] = v;
      }
}

// ---------------- RoPE on Q (cols 0..2047) and K (cols 2048..2559) of Y ------
__global__ __launch_bounds__(256) void rope_k(u16* __restrict__ Y,
                                              const float* __restrict__ freq) {
  int idx = blockIdx.x * 256 + threadIdx.x;
  int s = idx / 1280;
  int rem = idx - s * 1280;
  int h = rem >> 5;
  int i = rem & 31;
  int col = (h < 32) ? (h * 64 + 2 * i) : (2048 + (h - 32) * 64 + 2 * i);
  float ang = freq[s * 32 + i];
  float sn, cs;
  sincosf(ang, &sn, &cs);
  size_t base = (size_t)s * 3072 + col;
  float e = bf2f(Y[base]), o = bf2f(Y[base + 1]);
  Y[base]     = f2bf(e * cs - o * sn);
  Y[base + 1] = f2bf(e * sn + o * cs);
}

// ---------------- Flash attention: causal GQA, pipelined, K/V from L2 --------
// One wave per block; 32 q-rows per wave. No steady-state cross-lane ops.
__global__ __launch_bounds__(64, 2) void attn_k(const u16* __restrict__ Y,
                                                const u16* __restrict__ Vtg,
                                                u16* __restrict__ Out) {
  __shared__ u32 Ps[2][16 * 36];
  const int bx = blockIdx.x;
  const int qh = bx & 31;
  const int ws = 63 - (bx >> 5);              // big tiles dispatched first
  const int kvh = qh >> 2;
  const int q0w = ws * 32;
  const int ntiles = (q0w >> 6) + 1;
  const int lane = threadIdx.x & 63;
  const int l15 = lane & 15, lq = lane >> 4;

  bf16x8 qf[2][2];
  #pragma unroll
  for (int qs = 0; qs < 2; ++qs)
    #pragma unroll
    for (int kk = 0; kk < 2; ++kk)
      qf[qs][kk] = *(const bf16x8*)&Y[(size_t)(q0w + qs * 16 + l15) * 3072 +
                                      qh * 64 + kk * 32 + lq * 8];

  float m_[2] = { -INFINITY, -INFINITY };
  float l_[2] = { 0.f, 0.f };                 // per-lane PARTIAL sums
  f32x4 accO[2][4] = {};
  constexpr float SC = 0.18033688011112042f;  // log2(e)/8

  const u16* Kg = Y + 2048 + kvh * 64 + (size_t)l15 * 3072 + lq * 8;
  const u16* Vg = Vtg + (size_t)(kvh * 64 + l15) * 2048 + lq * 8;

  auto loadK = [&](bf16x8 (&kf)[2][4], int t0) {
    #pragma unroll
    for (int kt = 0; kt < 4; ++kt)
      #pragma unroll
      for (int kk = 0; kk < 2; ++kk)
        kf[kk][kt] = *(const bf16x8*)&Kg[(size_t)(t0 + kt * 16) * 3072 + kk * 32];
  };

  auto body = [&](int t, bf16x8 (&kcur)[2][4], bf16x8 (&knxt)[2][4]) {
    const int t0 = t * 64;
    // V fragments for current tile — latency covered by QK^T + softmax
    bf16x8 vf[4][2];
    #pragma unroll
    for (int dt = 0; dt < 4; ++dt)
      #pragma unroll
      for (int c = 0; c < 2; ++c)
        vf[dt][c] = *(const bf16x8*)&Vg[(size_t)(dt * 16) * 2048 + t0 + c * 32];
    // prefetch next tile's K — latency covered by the whole tile body
    loadK(knxt, (t + 1 < ntiles ? t + 1 : t) * 64);

    // S^T = K Q^T : col=q (l15), row=kv (16*kt + 4*lq + r)
    f32x4 sc[2][4] = {};
    #pragma unroll
    for (int kk = 0; kk < 2; ++kk)
      #pragma unroll
      for (int kt = 0; kt < 4; ++kt) {
        sc[0][kt] = __builtin_amdgcn_mfma_f32_16x16x32_bf16(kcur[kk][kt], qf[0][kk], sc[0][kt], 0, 0, 0);
        sc[1][kt] = __builtin_amdgcn_mfma_f32_16x16x32_bf16(kcur[kk][kt], qf[1][kk], sc[1][kt], 0, 0, 0);
      }

    const bool lastt = (t == ntiles - 1);
    #pragma unroll
    for (int qs = 0; qs < 2; ++qs) {
      const int qrow = q0w + qs * 16 + l15;
      if (lastt) {
        #pragma unroll
        for (int n = 0; n < 4; ++n)
          #pragma unroll
          for (int r = 0; r < 4; ++r)
            if (t0 + n * 16 + lq * 4 + r > qrow) sc[qs][n][r] = -INFINITY;
      }
      // per-lane local max (no cross-lane in steady state)
      float a0 = fmaxf(fmaxf(sc[qs][0][0], sc[qs][0][1]), fmaxf(sc[qs][0][2], sc[qs][0][3]));
      float a1 = fmaxf(fmaxf(sc[qs][1][0], sc[qs][1][1]), fmaxf(sc[qs][1][2], sc[qs][1][3]));
      float a2 = fmaxf(fmaxf(sc[qs][2][0], sc[qs][2][1]), fmaxf(sc[qs][2][2], sc[qs][2][3]));
      float a3 = fmaxf(fmaxf(sc[qs][3][0], sc[qs][3][1]), fmaxf(sc[qs][3][2], sc[qs][3][3]));
      float mx = fmaxf(fmaxf(a0, a1), fmaxf(a2, a3));

      if (__any(mx > m_[qs] + 40.0f)) {        // rare: running max grew
        float mf = mx;
        mf = fmaxf(mf, __shfl_xor(mf, 16));
        mf = fmaxf(mf, __shfl_xor(mf, 32));
        const float mnew = fmaxf(m_[qs], mf);
        const float alpha = exp2f((m_[qs] - mnew) * SC);
        l_[qs] *= alpha;
        #pragma unroll
        for (int dt = 0; dt < 4; ++dt) accO[qs][dt] *= alpha;
        m_[qs] = mnew;
      }
      const float mS = m_[qs] * SC;
      float s0 = 0.f, s1 = 0.f, s2 = 0.f, s3 = 0.f;
      u32* pp = &Ps[qs][l15 * 36 + lq * 2];
      #pragma unroll
      for (int n = 0; n < 4; ++n) {
        float p0 = exp2f(sc[qs][n][0] * SC - mS);
        float p1 = exp2f(sc[qs][n][1] * SC - mS);
        float p2 = exp2f(sc[qs][n][2] * SC - mS);
        float p3 = exp2f(sc[qs][n][3] * SC - mS);
        s0 += p0; s1 += p1; s2 += p2; s3 += p3;
        u32 w0, w1;
        asm("v_cvt_pk_bf16_f32 %0, %1, %2" : "=v"(w0) : "v"(p0), "v"(p1));
        asm("v_cvt_pk_bf16_f32 %0, %1, %2" : "=v"(w1) : "v"(p2), "v"(p3));
        pp[n * 8] = w0; pp[n * 8 + 1] = w1;
      }
      l_[qs] += (s0 + s1) + (s2 + s3);
    }

    // O^T += V^T P^T  (both qs after both softmaxes: fills P write->read gap)
    #pragma unroll
    for (int qs = 0; qs < 2; ++qs) {
      const u16* p16 = (const u16*)Ps[qs];
      #pragma unroll
      for (int c = 0; c < 2; ++c) {
        bf16x8 b = *(const bf16x8*)&p16[l15 * 72 + c * 32 + lq * 8];
        #pragma unroll
        for (int dt = 0; dt < 4; ++dt)
          accO[qs][dt] = __builtin_amdgcn_mfma_f32_16x16x32_bf16(vf[dt][c], b, accO[qs][dt], 0, 0, 0);
      }
    }
  };

  bf16x8 kfA[2][4], kfB[2][4];
  loadK(kfA, 0);
  int t = 0;
  for (; t + 2 <= ntiles; t += 2) {
    body(t, kfA, kfB);
    body(t + 1, kfB, kfA);
  }
  if (t < ntiles) body(t, kfA, kfB);

  #pragma unroll
  for (int qs = 0; qs < 2; ++qs) {
    float lt = l_[qs];                         // cross-lane reduce ONCE
    lt += __shfl_xor(lt, 16);
    lt += __shfl_xor(lt, 32);
    const float rl = 1.0f / lt;
    const int qrow = q0w + qs * 16 + l15;
    #pragma unroll
    for (int dt = 0; dt < 4; ++dt) {
      ushort4 o;
      o.x = f2bf(accO[qs][dt][0] * rl);
      o.y = f2bf(accO[qs][dt][1] * rl);
      o.z = f2bf(accO[qs][dt][2] * rl);
      o.w = f2bf(accO[qs][dt][3] * rl);
      *(ushort4*)&Out[(size_t)qrow * 2048 + qh * 64 + dt * 16 + lq * 4] = o;
    }
  }
}

extern "C" void kernel_launch(void* const* d_in, const int* in_sizes, int n_in,
                              void* d_out, int out_size, void* d_ws, size_t ws_size,
                              hipStream_t stream) {
  const float* x    = (const float*)d_in[0];
  const float* freq = (const float*)d_in[1];
  // d_in[2] = mask (known causal tril; not read)
  const float* wq   = (const float*)d_in[3];
  const float* wk   = (const float*)d_in[4];
  const float* wv   = (const float*)d_in[5];
  const float* wo   = (const float*)d_in[6];
  float* out = (float*)d_out;

  u16* x_bf   = (u16*)d_ws;                       // 2048*2048  (reused as Vt later)
  u16* wqkv_t = x_bf + (size_t)2048 * 2048;       // [3072][2048]
  u16* wo_t   = wqkv_t + (size_t)3072 * 2048;     // [2048][2048]
  u16* y      = wo_t + (size_t)2048 * 2048;       // [2048][3072] = Q | K | V
  u16* attn   = y + (size_t)2048 * 3072;          // [2048][2048]
  u16* vt     = x_bf;                             // [512][2048]  (x_bf dead after QKV GEMM)

  cvt_f32_bf16_k<<<4096, 256, 0, stream>>>(x, x_bf, 2048 * 2048 / 4);
  transpose_cvt_k<<<dim3(64, 64), 256, 0, stream>>>(wq, wqkv_t, 2048, 2048);
  transpose_cvt_k<<<dim3(16, 64), 256, 0, stream>>>(wk, wqkv_t + (size_t)2048 * 2048, 2048, 512);
  transpose_cvt_k<<<dim3(16, 64), 256, 0, stream>>>(wv, wqkv_t + (size_t)2560 * 2048, 2048, 512);
  transpose_cvt_k<<<dim3(64, 64), 256, 0, stream>>>(wo, wo_t, 2048, 2048);

  gemm64_k<u16><<<dim3(24, 32), 256, 0, stream>>>(x_bf, wqkv_t, y, 2048, 3072, 2048);
  rope_k<<<10240, 256, 0, stream>>>(y, freq);
  vtrans_k<<<dim3(32, 8), 256, 0, stream>>>(y, vt);
  attn_k<<<2048, 64, 0, stream>>>(y, vt, attn);
  gemm64_k<float><<<dim3(16, 32), 256, 0, stream>>>(attn, wo_t, out, 2048, 2048, 2048);
}